// Round 6
// baseline (101.025 us; speedup 1.0000x reference)
//
#include <hip/hip_runtime.h>
#include <math.h>

#define N2   256
#define DIM  768
#define EPSF 1e-8f

// ws layout (float offsets). Every word is written before read on every call
// -> no zero-init needed despite 0xAA poison. Total ~5.26 MB.
#define OFF_PART  0u          // [8][2][65536] split-K partial Grams (4 MB)
#define OFF_PDIAG 1048576u    // [8][2][256]   partial diagonals
#define OFF_TSUM  1052672u    // [2][8][16]    per-tile partial sums (mat-major)
#define OFF_GS    1052928u    // [65536]
#define OFF_GT    1118464u    // [65536]
#define OFF_INVS  1184000u    // [65536]
#define OFF_INVT  1249536u    // [65536]

__device__ inline float wave_reduce_sum(float v) {
    #pragma unroll
    for (int o = 32; o > 0; o >>= 1) v += __shfl_down(v, o, 64);
    return v;
}
__device__ inline float wave_reduce_max(float v) {
    #pragma unroll
    for (int o = 32; o > 0; o >>= 1) v = fmaxf(v, __shfl_down(v, o, 64));
    return v;
}
__device__ inline float block_reduce_sum(float v, volatile float* red) {
    float w = wave_reduce_sum(v);
    __syncthreads();
    if ((threadIdx.x & 63) == 0) red[threadIdx.x >> 6] = w;
    __syncthreads();
    return red[0] + red[1] + red[2] + red[3];
}
__device__ inline const float* rowptr(const float* q, const float* p, int r) {
    return (r < 128) ? (q + r * DIM) : (p + (r - 128) * DIM);
}

// ---------------------------------------------------------------------------
// K1: Gram GEMM, split-K-8. 256 blocks x 256 threads.
// b&7 = K-chunk (96), (b>>3)&1 = matrix, b>>4 = 64x64 tile (4x4 grid).
// Writes partial Gram + partial diagonal + partial tile-sum. Block 0 also
// zeroes out[0..2] (kernel boundary makes it visible to K2/K3 atomics).
// ---------------------------------------------------------------------------
__global__ __launch_bounds__(256) void gemm_kernel(
        const float* __restrict__ sq, const float* __restrict__ sp,
        const float* __restrict__ tq, const float* __restrict__ tp,
        float* __restrict__ ws, float* __restrict__ out) {
    const int b = blockIdx.x, t = threadIdx.x;
    if (b == 0 && t < 3) out[t] = 0.f;
    const int c = b & 7, mat = (b >> 3) & 1, tile = b >> 4;
    const int m0 = (tile >> 2) * 64, n0 = (tile & 3) * 64;
    const float* q = mat ? tq : sq;
    const float* p = mat ? tp : sp;

    __shared__ float As[64][100];   // 96 k + pad (b128 reads ~2-way = free)
    __shared__ float Bs[64][100];
    __shared__ float redg[4];

    const int srow = t >> 2, skq = (t & 3) * 4;
    const int kb = c * 96;
    const float* arow = rowptr(q, p, m0 + srow);
    const float* brow = rowptr(q, p, n0 + srow);
    #pragma unroll
    for (int m = 0; m < 6; ++m) {
        *(float4*)&As[srow][skq + 16 * m] = *(const float4*)&arow[kb + skq + 16 * m];
        *(float4*)&Bs[srow][skq + 16 * m] = *(const float4*)&brow[kb + skq + 16 * m];
    }
    __syncthreads();

    const int ty = t >> 4, tx = t & 15;
    float acc[4][4] = {};
    for (int k = 0; k < 96; k += 4) {
        float4 av[4], bv[4];
        #pragma unroll
        for (int r = 0; r < 4; ++r) av[r] = *(const float4*)&As[ty + 16 * r][k];
        #pragma unroll
        for (int cc = 0; cc < 4; ++cc) bv[cc] = *(const float4*)&Bs[tx + 16 * cc][k];
        #pragma unroll
        for (int r = 0; r < 4; ++r) {
            const float ar4[4] = {av[r].x, av[r].y, av[r].z, av[r].w};
            #pragma unroll
            for (int cc = 0; cc < 4; ++cc) {
                const float bc4[4] = {bv[cc].x, bv[cc].y, bv[cc].z, bv[cc].w};
                acc[r][cc] = fmaf(ar4[0], bc4[0], acc[r][cc]);
                acc[r][cc] = fmaf(ar4[1], bc4[1], acc[r][cc]);
                acc[r][cc] = fmaf(ar4[2], bc4[2], acc[r][cc]);
                acc[r][cc] = fmaf(ar4[3], bc4[3], acc[r][cc]);
            }
        }
    }
    float* P = ws + OFF_PART + (unsigned)(c * 2 + mat) * 65536u;
    float ts = 0.f;
    #pragma unroll
    for (int r = 0; r < 4; ++r) {
        const int row = m0 + ty + 16 * r;
        #pragma unroll
        for (int cc = 0; cc < 4; ++cc) {
            P[row * 256 + n0 + tx + 16 * cc] = acc[r][cc];
            ts += acc[r][cc];
        }
    }
    if (m0 == n0 && ty == tx) {
        float* PD = ws + OFF_PDIAG + (unsigned)(c * 2 + mat) * 256u;
        #pragma unroll
        for (int r = 0; r < 4; ++r) PD[m0 + ty + 16 * r] = acc[r][r];
    }
    const float tsum = block_reduce_sum(ts, redg);
    if (t == 0) ws[OFF_TSUM + (unsigned)(mat * 128 + c * 16 + tile)] = tsum;
}

// ---------------------------------------------------------------------------
// K2: sum partials (both mats) -> G, inv; analytic distance means
// (sum_ds = N*tr - sum_all); dist row huber; contrastive (rows < 128).
// 256 blocks x 256 threads: block = row i, thread = column j.
// All results atomicAdd'ed (pre-scaled) into out — no slots, no finalize.
// ---------------------------------------------------------------------------
__global__ __launch_bounds__(256) void prep_kernel(float* __restrict__ ws,
                                                   float* __restrict__ out) {
    __shared__ float red1[4], red2[4], redS[1];
    const int i = blockIdx.x, j = threadIdx.x, t = threadIdx.x;

    const float* P  = ws + OFF_PART;
    const float* PD = ws + OFF_PDIAG;
    float gs = 0.f, gt = 0.f, djs = 0.f, djt = 0.f, dis = 0.f, dit = 0.f;
    #pragma unroll
    for (int c = 0; c < 8; ++c) {
        gs  += P[c * 131072 + i * 256 + j];
        gt  += P[c * 131072 + 65536 + i * 256 + j];
        djs += PD[c * 512 + j];
        djt += PD[c * 512 + 256 + j];
        dis += PD[c * 512 + i];
        dit += PD[c * 512 + 256 + i];
    }
    (ws + OFF_GS)[i * 256 + j] = gs;
    (ws + OFF_GT)[i * 256 + j] = gt;
    const float ds = fmaxf(dis + djs - 2.f * gs, 0.f);
    const float dt = fmaxf(dit + djt - 2.f * gt, 0.f);
    (ws + OFF_INVS)[i * 256 + j] = 1.f / (sqrtf(ds) + EPSF);
    (ws + OFF_INVT)[i * 256 + j] = 1.f / (sqrtf(dt) + EPSF);

    // analytic masked pair-sums: sum_{i<j} d = N*tr - sum_all(G)
    const float tr_s = block_reduce_sum(djs, red1);
    const float tr_t = block_reduce_sum(djt, red1);
    const float tv = ws[OFF_TSUM + t];
    const float sum_gs = block_reduce_sum((t < 128) ? tv : 0.f, red1);
    const float sum_gt = block_reduce_sum((t >= 128) ? tv : 0.f, red1);
    const float rs = 1.f / ((256.f * tr_s - sum_gs) / 32640.f + EPSF);
    const float rt = 1.f / ((256.f * tr_t - sum_gt) / 32640.f + EPSF);

    // distance loss row
    const float dd = ds * rs - dt * rt;
    const float a = fabsf(dd);
    const float m = fminf(a, 1.f);
    const float hv = block_reduce_sum((j > i) ? m * fmaf(-0.5f, m, a) : 0.f, red1);
    if (t == 0) {
        const float c0 = 0.5f * hv / 32640.f;
        atomicAdd(&out[0], c0);
        atomicAdd(&out[2], c0);
    }

    if (i < 128) {  // contrastive row i (block-uniform branch)
        const float s = (j >= 128) ? 20.f * gs : -INFINITY;
        if (j == 128 + i) redS[0] = s;          // diag score
        float mx0 = wave_reduce_max(s);
        __syncthreads();
        if ((t & 63) == 0) red2[t >> 6] = mx0;
        __syncthreads();
        const float mx = fmaxf(fmaxf(red2[0], red2[1]), fmaxf(red2[2], red2[3]));
        const float e = block_reduce_sum((j >= 128) ? expf(s - mx) : 0.f, red1);
        if (t == 0) {
            const float cb = (mx + logf(e) - redS[0]) / 128.f;
            atomicAdd(&out[0], cb);
            atomicAdd(&out[1], cb);
        }
    }
}

// ---------------------------------------------------------------------------
// K3: angle. 512 blocks x 256 threads; contributions atomicAdd'ed into out.
// Maskless: excluded diagonals contribute exactly/negligibly 0.
// ---------------------------------------------------------------------------
__global__ __launch_bounds__(256) void angle_kernel(float* __restrict__ ws,
                                                    float* __restrict__ out) {
    const float* Gs = ws + OFF_GS;
    const float* Gt = ws + OFF_GT;
    const float* IS = ws + OFF_INVS;
    const float* IT = ws + OFF_INVT;
    __shared__ float sGJ[16][68], sIJ[16][68], sTJ[16][68], sITJ[16][68];
    __shared__ float red1[4];
    const int b = blockIdx.x, t = threadIdx.x;

    const int k0 = (b & 3) * 64;
    const int j0 = ((b >> 2) & 15) * 16;
    const int i0 = (b >> 6) * 32;
    const int jj = t & 15, ii = t >> 4;
    const int i1 = i0 + ii, i2 = i1 + 16, j = j0 + jj;
    {
        const int r = t >> 4, c = (t & 15) * 4;
        const int g = (j0 + r) * N2 + k0 + c;
        *(float4*)&sGJ[r][c]  = *(const float4*)&Gs[g];
        *(float4*)&sIJ[r][c]  = *(const float4*)&IS[g];
        *(float4*)&sTJ[r][c]  = *(const float4*)&Gt[g];
        *(float4*)&sITJ[r][c] = *(const float4*)&IT[g];
    }
    const float Gjj = Gs[j * 257], Tjj = Gt[j * 257];
    const float wis1 = IS[i1 * N2 + j], wit1 = IT[i1 * N2 + j];
    const float wis2 = IS[i2 * N2 + j], wit2 = IT[i2 * N2 + j];
    const float as1 = (Gjj - Gs[i1 * N2 + j]) * wis1;
    const float at1 = (Tjj - Gt[i1 * N2 + j]) * wit1;
    const float as2 = (Gjj - Gs[i2 * N2 + j]) * wis2;
    const float at2 = (Tjj - Gt[i2 * N2 + j]) * wit2;
    const float* gI1 = Gs + i1 * N2 + k0;
    const float* tI1 = Gt + i1 * N2 + k0;
    const float* gI2 = Gs + i2 * N2 + k0;
    const float* tI2 = Gt + i2 * N2 + k0;
    __syncthreads();

    float sum1 = 0.f, sum2 = 0.f;
    for (int c = 0; c < 64; c += 4) {
        const float4 gJ  = *(const float4*)&sGJ[jj][c];
        const float4 iJ  = *(const float4*)&sIJ[jj][c];
        const float4 tJ  = *(const float4*)&sTJ[jj][c];
        const float4 itJ = *(const float4*)&sITJ[jj][c];
        const float4 a1 = *(const float4*)&gI1[c];
        const float4 b1 = *(const float4*)&tI1[c];
        const float4 a2 = *(const float4*)&gI2[c];
        const float4 b2 = *(const float4*)&tI2[c];
        const float gJr[4]  = {gJ.x, gJ.y, gJ.z, gJ.w};
        const float iJr[4]  = {iJ.x, iJ.y, iJ.z, iJ.w};
        const float tJr[4]  = {tJ.x, tJ.y, tJ.z, tJ.w};
        const float itJr[4] = {itJ.x, itJ.y, itJ.z, itJ.w};
        const float a1r[4] = {a1.x, a1.y, a1.z, a1.w};
        const float b1r[4] = {b1.x, b1.y, b1.z, b1.w};
        const float a2r[4] = {a2.x, a2.y, a2.z, a2.w};
        const float b2r[4] = {b2.x, b2.y, b2.z, b2.w};
        #pragma unroll
        for (int e = 0; e < 4; ++e) {
            const float ps1 = fmaf(wis1, a1r[e] - gJr[e], as1) * iJr[e];
            const float pt1 = fmaf(wit1, b1r[e] - tJr[e], at1) * itJr[e];
            const float d1 = ps1 - pt1;
            const float ad1 = fabsf(d1);
            const float m1 = fminf(ad1, 1.f);
            sum1 = fmaf(m1, fmaf(-0.5f, m1, ad1), sum1);

            const float ps2 = fmaf(wis2, a2r[e] - gJr[e], as2) * iJr[e];
            const float pt2 = fmaf(wit2, b2r[e] - tJr[e], at2) * itJr[e];
            const float d2 = ps2 - pt2;
            const float ad2 = fabsf(d2);
            const float m2 = fminf(ad2, 1.f);
            sum2 = fmaf(m2, fmaf(-0.5f, m2, ad2), sum2);
        }
    }
    const float v = block_reduce_sum(sum1 + sum2, red1);
    if (t == 0) {
        const float c0 = 0.5f * v / 16581120.f;   // 256*255*254
        atomicAdd(&out[0], c0);
        atomicAdd(&out[2], c0);
    }
}

extern "C" void kernel_launch(void* const* d_in, const int* in_sizes, int n_in,
                              void* d_out, int out_size, void* d_ws, size_t ws_size,
                              hipStream_t stream) {
    (void)in_sizes; (void)n_in; (void)out_size; (void)ws_size;
    const float* sq = (const float*)d_in[0];
    const float* sp = (const float*)d_in[1];
    const float* tq = (const float*)d_in[2];
    const float* tp = (const float*)d_in[3];
    float* ws  = (float*)d_ws;
    float* out = (float*)d_out;

    gemm_kernel<<<256, 256, 0, stream>>>(sq, sp, tq, tp, ws, out);
    prep_kernel<<<256, 256, 0, stream>>>(ws, out);
    angle_kernel<<<512, 256, 0, stream>>>(ws, out);
}

// Round 7
// 84.171 us; speedup vs baseline: 1.2002x; 1.2002x over previous
//
#include <hip/hip_runtime.h>
#include <math.h>

#define N2   256
#define DIM  768
#define EPSF 1e-8f

// ws layout (float offsets). Every word is written before read on every call
// -> no zero-init needed despite 0xAA poison. Total ~5.26 MB.
// NOTE (measured R6): same-address device atomicAdd costs ~10us/1000 in tail
// serialization -> slots + 1-block finalize kernel is the faster pattern.
// NOTE (measured R4): __threadfence() in hot blocks = per-block L2 writeback/
// invalidate storm (60us angle). Kernel boundaries are the free coherence pt.
#define OFF_PART  0u          // [8][2][65536] split-K partial Grams (4 MB)
#define OFF_PDIAG 1048576u    // [8][2][256]   partial diagonals
#define OFF_TSUM  1052672u    // [2][8][16]    per-tile partial sums (mat-major)
#define OFF_GS    1052928u    // [65536]
#define OFF_GT    1118464u    // [65536]
#define OFF_INVS  1184000u    // [65536]
#define OFF_INVT  1249536u    // [65536]
#define OFF_SLOT  1315072u    // [896] per-block result slots
#define SL_ANG  0     // [512]
#define SL_DIST 512   // [256]
#define SL_CON  768   // [128]

__device__ inline float wave_reduce_sum(float v) {
    #pragma unroll
    for (int o = 32; o > 0; o >>= 1) v += __shfl_down(v, o, 64);
    return v;
}
__device__ inline float wave_reduce_max(float v) {
    #pragma unroll
    for (int o = 32; o > 0; o >>= 1) v = fmaxf(v, __shfl_down(v, o, 64));
    return v;
}
__device__ inline float block_reduce_sum(float v, volatile float* red) {
    float w = wave_reduce_sum(v);
    __syncthreads();
    if ((threadIdx.x & 63) == 0) red[threadIdx.x >> 6] = w;
    __syncthreads();
    return red[0] + red[1] + red[2] + red[3];
}
__device__ inline const float* rowptr(const float* q, const float* p, int r) {
    return (r < 128) ? (q + r * DIM) : (p + (r - 128) * DIM);
}

// ---------------------------------------------------------------------------
// K1: Gram GEMM, split-K-8. 256 blocks x 256 threads.
// b&7 = K-chunk (96), (b>>3)&1 = matrix, b>>4 = 64x64 tile (4x4 grid).
// Writes partial Gram + partial diagonal + partial tile-sum (for the
// analytic pair-sum). No atomics, no pre-zeroed memory.
// ---------------------------------------------------------------------------
__global__ __launch_bounds__(256) void gemm_kernel(
        const float* __restrict__ sq, const float* __restrict__ sp,
        const float* __restrict__ tq, const float* __restrict__ tp,
        float* __restrict__ ws) {
    const int b = blockIdx.x, t = threadIdx.x;
    const int c = b & 7, mat = (b >> 3) & 1, tile = b >> 4;
    const int m0 = (tile >> 2) * 64, n0 = (tile & 3) * 64;
    const float* q = mat ? tq : sq;
    const float* p = mat ? tp : sp;

    __shared__ float As[64][100];   // 96 k + pad (b128 reads ~2-way = free)
    __shared__ float Bs[64][100];
    __shared__ float redg[4];

    const int srow = t >> 2, skq = (t & 3) * 4;
    const int kb = c * 96;
    const float* arow = rowptr(q, p, m0 + srow);
    const float* brow = rowptr(q, p, n0 + srow);
    #pragma unroll
    for (int m = 0; m < 6; ++m) {
        *(float4*)&As[srow][skq + 16 * m] = *(const float4*)&arow[kb + skq + 16 * m];
        *(float4*)&Bs[srow][skq + 16 * m] = *(const float4*)&brow[kb + skq + 16 * m];
    }
    __syncthreads();

    const int ty = t >> 4, tx = t & 15;
    float acc[4][4] = {};
    for (int k = 0; k < 96; k += 4) {
        float4 av[4], bv[4];
        #pragma unroll
        for (int r = 0; r < 4; ++r) av[r] = *(const float4*)&As[ty + 16 * r][k];
        #pragma unroll
        for (int cc = 0; cc < 4; ++cc) bv[cc] = *(const float4*)&Bs[tx + 16 * cc][k];
        #pragma unroll
        for (int r = 0; r < 4; ++r) {
            const float ar4[4] = {av[r].x, av[r].y, av[r].z, av[r].w};
            #pragma unroll
            for (int cc = 0; cc < 4; ++cc) {
                const float bc4[4] = {bv[cc].x, bv[cc].y, bv[cc].z, bv[cc].w};
                acc[r][cc] = fmaf(ar4[0], bc4[0], acc[r][cc]);
                acc[r][cc] = fmaf(ar4[1], bc4[1], acc[r][cc]);
                acc[r][cc] = fmaf(ar4[2], bc4[2], acc[r][cc]);
                acc[r][cc] = fmaf(ar4[3], bc4[3], acc[r][cc]);
            }
        }
    }
    float* P = ws + OFF_PART + (unsigned)(c * 2 + mat) * 65536u;
    float ts = 0.f;
    #pragma unroll
    for (int r = 0; r < 4; ++r) {
        const int row = m0 + ty + 16 * r;
        #pragma unroll
        for (int cc = 0; cc < 4; ++cc) {
            P[row * 256 + n0 + tx + 16 * cc] = acc[r][cc];
            ts += acc[r][cc];
        }
    }
    if (m0 == n0 && ty == tx) {
        float* PD = ws + OFF_PDIAG + (unsigned)(c * 2 + mat) * 256u;
        #pragma unroll
        for (int r = 0; r < 4; ++r) PD[m0 + ty + 16 * r] = acc[r][r];
    }
    const float tsum = block_reduce_sum(ts, redg);
    if (t == 0) ws[OFF_TSUM + (unsigned)(mat * 128 + c * 16 + tile)] = tsum;
}

// ---------------------------------------------------------------------------
// K2: sum partials (both mats) -> G, inv; analytic distance means
// (sum_{i<j} ds = N*tr - sum_all); dist row huber -> slot; contrastive
// (rows < 128) -> slot. 256 blocks x 256 threads: block = row i, thread = j.
// ---------------------------------------------------------------------------
__global__ __launch_bounds__(256) void prep_kernel(float* __restrict__ ws) {
    __shared__ float red1[4], red2[4], redS[1];
    const int i = blockIdx.x, j = threadIdx.x, t = threadIdx.x;

    const float* P  = ws + OFF_PART;
    const float* PD = ws + OFF_PDIAG;
    float gs = 0.f, gt = 0.f, djs = 0.f, djt = 0.f, dis = 0.f, dit = 0.f;
    #pragma unroll
    for (int c = 0; c < 8; ++c) {
        gs  += P[c * 131072 + i * 256 + j];
        gt  += P[c * 131072 + 65536 + i * 256 + j];
        djs += PD[c * 512 + j];
        djt += PD[c * 512 + 256 + j];
        dis += PD[c * 512 + i];
        dit += PD[c * 512 + 256 + i];
    }
    (ws + OFF_GS)[i * 256 + j] = gs;
    (ws + OFF_GT)[i * 256 + j] = gt;
    const float ds = fmaxf(dis + djs - 2.f * gs, 0.f);
    const float dt = fmaxf(dit + djt - 2.f * gt, 0.f);
    (ws + OFF_INVS)[i * 256 + j] = 1.f / (sqrtf(ds) + EPSF);
    (ws + OFF_INVT)[i * 256 + j] = 1.f / (sqrtf(dt) + EPSF);

    // analytic masked pair-sums: sum_{i<j} d = N*tr - sum_all(G)
    const float tr_s = block_reduce_sum(djs, red1);
    const float tr_t = block_reduce_sum(djt, red1);
    const float tv = ws[OFF_TSUM + t];
    const float sum_gs = block_reduce_sum((t < 128) ? tv : 0.f, red1);
    const float sum_gt = block_reduce_sum((t >= 128) ? tv : 0.f, red1);
    const float rs = 1.f / ((256.f * tr_s - sum_gs) / 32640.f + EPSF);
    const float rt = 1.f / ((256.f * tr_t - sum_gt) / 32640.f + EPSF);

    // distance loss row -> slot
    const float dd = ds * rs - dt * rt;
    const float a = fabsf(dd);
    const float m = fminf(a, 1.f);
    const float hv = block_reduce_sum((j > i) ? m * fmaf(-0.5f, m, a) : 0.f, red1);
    if (t == 0) ws[OFF_SLOT + SL_DIST + i] = hv;

    if (i < 128) {  // contrastive row i (block-uniform branch)
        const float s = (j >= 128) ? 20.f * gs : -INFINITY;
        if (j == 128 + i) redS[0] = s;          // diag score
        float mx0 = wave_reduce_max(s);
        __syncthreads();
        if ((t & 63) == 0) red2[t >> 6] = mx0;
        __syncthreads();
        const float mx = fmaxf(fmaxf(red2[0], red2[1]), fmaxf(red2[2], red2[3]));
        const float e = block_reduce_sum((j >= 128) ? expf(s - mx) : 0.f, red1);
        if (t == 0) ws[OFF_SLOT + SL_CON + i] = mx + logf(e) - redS[0];
    }
}

// ---------------------------------------------------------------------------
// K3: angle. 512 blocks x 256 threads; per-block sum -> slot (plain store).
// Maskless: excluded diagonals contribute exactly/negligibly 0.
// ---------------------------------------------------------------------------
__global__ __launch_bounds__(256) void angle_kernel(float* __restrict__ ws) {
    const float* Gs = ws + OFF_GS;
    const float* Gt = ws + OFF_GT;
    const float* IS = ws + OFF_INVS;
    const float* IT = ws + OFF_INVT;
    __shared__ float sGJ[16][68], sIJ[16][68], sTJ[16][68], sITJ[16][68];
    __shared__ float red1[4];
    const int b = blockIdx.x, t = threadIdx.x;

    const int k0 = (b & 3) * 64;
    const int j0 = ((b >> 2) & 15) * 16;
    const int i0 = (b >> 6) * 32;
    const int jj = t & 15, ii = t >> 4;
    const int i1 = i0 + ii, i2 = i1 + 16, j = j0 + jj;
    {
        const int r = t >> 4, c = (t & 15) * 4;
        const int g = (j0 + r) * N2 + k0 + c;
        *(float4*)&sGJ[r][c]  = *(const float4*)&Gs[g];
        *(float4*)&sIJ[r][c]  = *(const float4*)&IS[g];
        *(float4*)&sTJ[r][c]  = *(const float4*)&Gt[g];
        *(float4*)&sITJ[r][c] = *(const float4*)&IT[g];
    }
    const float Gjj = Gs[j * 257], Tjj = Gt[j * 257];
    const float wis1 = IS[i1 * N2 + j], wit1 = IT[i1 * N2 + j];
    const float wis2 = IS[i2 * N2 + j], wit2 = IT[i2 * N2 + j];
    const float as1 = (Gjj - Gs[i1 * N2 + j]) * wis1;
    const float at1 = (Tjj - Gt[i1 * N2 + j]) * wit1;
    const float as2 = (Gjj - Gs[i2 * N2 + j]) * wis2;
    const float at2 = (Tjj - Gt[i2 * N2 + j]) * wit2;
    const float* gI1 = Gs + i1 * N2 + k0;
    const float* tI1 = Gt + i1 * N2 + k0;
    const float* gI2 = Gs + i2 * N2 + k0;
    const float* tI2 = Gt + i2 * N2 + k0;
    __syncthreads();

    float sum1 = 0.f, sum2 = 0.f;
    for (int c = 0; c < 64; c += 4) {
        const float4 gJ  = *(const float4*)&sGJ[jj][c];
        const float4 iJ  = *(const float4*)&sIJ[jj][c];
        const float4 tJ  = *(const float4*)&sTJ[jj][c];
        const float4 itJ = *(const float4*)&sITJ[jj][c];
        const float4 a1 = *(const float4*)&gI1[c];
        const float4 b1 = *(const float4*)&tI1[c];
        const float4 a2 = *(const float4*)&gI2[c];
        const float4 b2 = *(const float4*)&tI2[c];
        const float gJr[4]  = {gJ.x, gJ.y, gJ.z, gJ.w};
        const float iJr[4]  = {iJ.x, iJ.y, iJ.z, iJ.w};
        const float tJr[4]  = {tJ.x, tJ.y, tJ.z, tJ.w};
        const float itJr[4] = {itJ.x, itJ.y, itJ.z, itJ.w};
        const float a1r[4] = {a1.x, a1.y, a1.z, a1.w};
        const float b1r[4] = {b1.x, b1.y, b1.z, b1.w};
        const float a2r[4] = {a2.x, a2.y, a2.z, a2.w};
        const float b2r[4] = {b2.x, b2.y, b2.z, b2.w};
        #pragma unroll
        for (int e = 0; e < 4; ++e) {
            const float ps1 = fmaf(wis1, a1r[e] - gJr[e], as1) * iJr[e];
            const float pt1 = fmaf(wit1, b1r[e] - tJr[e], at1) * itJr[e];
            const float d1 = ps1 - pt1;
            const float ad1 = fabsf(d1);
            const float m1 = fminf(ad1, 1.f);
            sum1 = fmaf(m1, fmaf(-0.5f, m1, ad1), sum1);

            const float ps2 = fmaf(wis2, a2r[e] - gJr[e], as2) * iJr[e];
            const float pt2 = fmaf(wit2, b2r[e] - tJr[e], at2) * itJr[e];
            const float d2 = ps2 - pt2;
            const float ad2 = fabsf(d2);
            const float m2 = fminf(ad2, 1.f);
            sum2 = fmaf(m2, fmaf(-0.5f, m2, ad2), sum2);
        }
    }
    const float v = block_reduce_sum(sum1 + sum2, red1);
    if (t == 0) ws[OFF_SLOT + SL_ANG + b] = v;
}

// ---------------------------------------------------------------------------
// K4: finalize. 1 block x 256 threads; kernel boundary = coherence point.
// ---------------------------------------------------------------------------
__global__ __launch_bounds__(256) void finalize_kernel(const float* __restrict__ ws,
                                                       float* __restrict__ out) {
    __shared__ float red1[4];
    const int t = threadIdx.x;
    const float* S = ws + OFF_SLOT;
    const float a_ = block_reduce_sum(S[SL_ANG + t] + S[SL_ANG + 256 + t], red1);
    const float d_ = block_reduce_sum(S[SL_DIST + t], red1);
    const float c_ = block_reduce_sum((t < 128) ? S[SL_CON + t] : 0.f, red1);
    if (t == 0) {
        const float contrastive = c_ / 128.f;
        const float dist = d_ / 32640.f;
        const float ang = a_ / 16581120.f;   // 256*255*254
        const float kd = 0.5f * (dist + ang);
        out[0] = contrastive + kd;
        out[1] = contrastive;
        out[2] = kd;
    }
}

extern "C" void kernel_launch(void* const* d_in, const int* in_sizes, int n_in,
                              void* d_out, int out_size, void* d_ws, size_t ws_size,
                              hipStream_t stream) {
    (void)in_sizes; (void)n_in; (void)out_size; (void)ws_size;
    const float* sq = (const float*)d_in[0];
    const float* sp = (const float*)d_in[1];
    const float* tq = (const float*)d_in[2];
    const float* tp = (const float*)d_in[3];
    float* ws  = (float*)d_ws;
    float* out = (float*)d_out;

    gemm_kernel<<<256, 256, 0, stream>>>(sq, sp, tq, tp, ws);
    prep_kernel<<<256, 256, 0, stream>>>(ws);
    angle_kernel<<<512, 256, 0, stream>>>(ws);
    finalize_kernel<<<1, 256, 0, stream>>>(ws, out);
}

// Round 8
// 83.591 us; speedup vs baseline: 1.2086x; 1.0069x over previous
//
#include <hip/hip_runtime.h>
#include <math.h>

#define N2   256
#define DIM  768
#define EPSF 1e-8f

// ws layout (float offsets). Every word is written before read on every call
// -> no zero-init needed despite 0xAA poison. Total ~4.2 MB.
// NOTE (measured R6): same-address device atomicAdd costs ~10us/1000 in tail
// serialization -> slots + 1-block finalize kernel is the faster pattern.
// NOTE (measured R4): __threadfence() in hot blocks = per-block L2 writeback/
// invalidate storm (60us angle). Kernel boundaries are the free coherence pt.
// NOTE (R8): prep kernel deleted — consumers sum the 8 split-K partials
// inline (bit-identical order) and compute INV on the fly; one fewer node.
#define OFF_PART  0u          // [8][2][65536] split-K partial Grams (4 MB)
#define OFF_PDIAG 1048576u    // [8][2][256]   partial diagonals
#define OFF_TSUM  1052672u    // [2][8][16]    per-tile partial sums (mat-major)
#define OFF_SLOT  1052928u    // [896] per-block result slots
#define SL_ANG  0     // [512]
#define SL_DIST 512   // [256]
#define SL_CON  768   // [128]

__device__ inline float wave_reduce_sum(float v) {
    #pragma unroll
    for (int o = 32; o > 0; o >>= 1) v += __shfl_down(v, o, 64);
    return v;
}
__device__ inline float wave_reduce_max(float v) {
    #pragma unroll
    for (int o = 32; o > 0; o >>= 1) v = fmaxf(v, __shfl_down(v, o, 64));
    return v;
}
__device__ inline float block_reduce_sum(float v, volatile float* red) {
    float w = wave_reduce_sum(v);
    __syncthreads();
    if ((threadIdx.x & 63) == 0) red[threadIdx.x >> 6] = w;
    __syncthreads();
    return red[0] + red[1] + red[2] + red[3];
}
__device__ inline const float* rowptr(const float* q, const float* p, int r) {
    return (r < 128) ? (q + r * DIM) : (p + (r - 128) * DIM);
}

// ---------------------------------------------------------------------------
// K1: Gram GEMM, split-K-8. 256 blocks x 256 threads.
// b&7 = K-chunk (96), (b>>3)&1 = matrix, b>>4 = 64x64 tile (4x4 grid).
// Writes partial Gram + partial diagonal + partial tile-sum.
// ---------------------------------------------------------------------------
__global__ __launch_bounds__(256) void gemm_kernel(
        const float* __restrict__ sq, const float* __restrict__ sp,
        const float* __restrict__ tq, const float* __restrict__ tp,
        float* __restrict__ ws) {
    const int b = blockIdx.x, t = threadIdx.x;
    const int c = b & 7, mat = (b >> 3) & 1, tile = b >> 4;
    const int m0 = (tile >> 2) * 64, n0 = (tile & 3) * 64;
    const float* q = mat ? tq : sq;
    const float* p = mat ? tp : sp;

    __shared__ float As[64][100];   // 96 k + pad (b128 reads ~2-way = free)
    __shared__ float Bs[64][100];
    __shared__ float redg[4];

    const int srow = t >> 2, skq = (t & 3) * 4;
    const int kb = c * 96;
    const float* arow = rowptr(q, p, m0 + srow);
    const float* brow = rowptr(q, p, n0 + srow);
    #pragma unroll
    for (int m = 0; m < 6; ++m) {
        *(float4*)&As[srow][skq + 16 * m] = *(const float4*)&arow[kb + skq + 16 * m];
        *(float4*)&Bs[srow][skq + 16 * m] = *(const float4*)&brow[kb + skq + 16 * m];
    }
    __syncthreads();

    const int ty = t >> 4, tx = t & 15;
    float acc[4][4] = {};
    for (int k = 0; k < 96; k += 4) {
        float4 av[4], bv[4];
        #pragma unroll
        for (int r = 0; r < 4; ++r) av[r] = *(const float4*)&As[ty + 16 * r][k];
        #pragma unroll
        for (int cc = 0; cc < 4; ++cc) bv[cc] = *(const float4*)&Bs[tx + 16 * cc][k];
        #pragma unroll
        for (int r = 0; r < 4; ++r) {
            const float ar4[4] = {av[r].x, av[r].y, av[r].z, av[r].w};
            #pragma unroll
            for (int cc = 0; cc < 4; ++cc) {
                const float bc4[4] = {bv[cc].x, bv[cc].y, bv[cc].z, bv[cc].w};
                acc[r][cc] = fmaf(ar4[0], bc4[0], acc[r][cc]);
                acc[r][cc] = fmaf(ar4[1], bc4[1], acc[r][cc]);
                acc[r][cc] = fmaf(ar4[2], bc4[2], acc[r][cc]);
                acc[r][cc] = fmaf(ar4[3], bc4[3], acc[r][cc]);
            }
        }
    }
    float* P = ws + OFF_PART + (unsigned)(c * 2 + mat) * 65536u;
    float ts = 0.f;
    #pragma unroll
    for (int r = 0; r < 4; ++r) {
        const int row = m0 + ty + 16 * r;
        #pragma unroll
        for (int cc = 0; cc < 4; ++cc) {
            P[row * 256 + n0 + tx + 16 * cc] = acc[r][cc];
            ts += acc[r][cc];
        }
    }
    if (m0 == n0 && ty == tx) {
        float* PD = ws + OFF_PDIAG + (unsigned)(c * 2 + mat) * 256u;
        #pragma unroll
        for (int r = 0; r < 4; ++r) PD[m0 + ty + 16 * r] = acc[r][r];
    }
    const float tsum = block_reduce_sum(ts, redg);
    if (t == 0) ws[OFF_TSUM + (unsigned)(mat * 128 + c * 16 + tile)] = tsum;
}

// ---------------------------------------------------------------------------
// K2: mega kernel. blocks 0..511 angle, 512..767 dist rows, 768..895
// contrastive rows. All consumers sum the 8 split-K partials inline
// (bit-identical to the old prep order) and compute diag/INV on the fly.
// ---------------------------------------------------------------------------
__global__ __launch_bounds__(256) void mega_kernel(float* __restrict__ ws) {
    const float* P  = ws + OFF_PART;
    const float* PD = ws + OFF_PDIAG;
    __shared__ float sGJ[16][68], sTJ[16][68], sIJ[16][68], sITJ[16][68];
    __shared__ float sGI[32][68], sTI[32][68];
    __shared__ float dgS[256], dgT[256];
    __shared__ float red1[4], red2[4], redS[1];
    const int b = blockIdx.x, t = threadIdx.x;

    if (b < 512) {
        // ---------------- angle ----------------
        const int k0 = (b & 3) * 64;
        const int j0 = ((b >> 2) & 15) * 16;
        const int i0 = (b >> 6) * 32;
        const int jj = t & 15, ii = t >> 4;
        const int i1 = i0 + ii, i2 = i1 + 16, j = j0 + jj;

        // diag sums (thread t owns index t)
        {
            float as = 0.f, at_ = 0.f;
            #pragma unroll
            for (int c = 0; c < 8; ++c) {
                as  += PD[c * 512 + t];
                at_ += PD[c * 512 + 256 + t];
            }
            dgS[t] = as; dgT[t] = at_;
        }
        // J-side G sums -> registers (1 float4 slot/thread)
        const int r = t >> 4, c4 = (t & 15) * 4;
        float4 gjs = {0,0,0,0}, gjt = {0,0,0,0};
        {
            const unsigned base = (unsigned)((j0 + r) * 256 + k0 + c4);
            #pragma unroll
            for (int c = 0; c < 8; ++c) {
                const float4 a = *(const float4*)&P[c * 131072u + base];
                const float4 e = *(const float4*)&P[c * 131072u + 65536u + base];
                gjs.x += a.x; gjs.y += a.y; gjs.z += a.z; gjs.w += a.w;
                gjt.x += e.x; gjt.y += e.y; gjt.z += e.z; gjt.w += e.w;
            }
        }
        // I-side G sums -> LDS (2 float4 slots/thread), no diag needed
        #pragma unroll
        for (int s2 = 0; s2 < 2; ++s2) {
            const int slot = t + 256 * s2;
            const int ri = slot >> 4, ci = (slot & 15) * 4;
            const unsigned base = (unsigned)((i0 + ri) * 256 + k0 + ci);
            float4 gs = {0,0,0,0}, gt = {0,0,0,0};
            #pragma unroll
            for (int c = 0; c < 8; ++c) {
                const float4 a = *(const float4*)&P[c * 131072u + base];
                const float4 e = *(const float4*)&P[c * 131072u + 65536u + base];
                gs.x += a.x; gs.y += a.y; gs.z += a.z; gs.w += a.w;
                gt.x += e.x; gt.y += e.y; gt.z += e.z; gt.w += e.w;
            }
            *(float4*)&sGI[ri][ci] = gs;
            *(float4*)&sTI[ri][ci] = gt;
        }
        // per-thread G[i1,j], G[i2,j] partial sums (both mats)
        float g1s = 0.f, g1t = 0.f, g2s = 0.f, g2t = 0.f;
        #pragma unroll
        for (int c = 0; c < 8; ++c) {
            g1s += P[c * 131072u + (unsigned)(i1 * 256 + j)];
            g1t += P[c * 131072u + 65536u + (unsigned)(i1 * 256 + j)];
            g2s += P[c * 131072u + (unsigned)(i2 * 256 + j)];
            g2t += P[c * 131072u + 65536u + (unsigned)(i2 * 256 + j)];
        }
        __syncthreads();   // dgS/dgT ready

        // write J arrays + on-the-fly INV
        {
            const float djs = dgS[j0 + r], djt = dgT[j0 + r];
            float4 ivs, ivt;
            const float* dS = &dgS[k0 + c4];
            const float* dT = &dgT[k0 + c4];
            ivs.x = 1.f / (sqrtf(fmaxf(djs + dS[0] - 2.f * gjs.x, 0.f)) + EPSF);
            ivs.y = 1.f / (sqrtf(fmaxf(djs + dS[1] - 2.f * gjs.y, 0.f)) + EPSF);
            ivs.z = 1.f / (sqrtf(fmaxf(djs + dS[2] - 2.f * gjs.z, 0.f)) + EPSF);
            ivs.w = 1.f / (sqrtf(fmaxf(djs + dS[3] - 2.f * gjs.w, 0.f)) + EPSF);
            ivt.x = 1.f / (sqrtf(fmaxf(djt + dT[0] - 2.f * gjt.x, 0.f)) + EPSF);
            ivt.y = 1.f / (sqrtf(fmaxf(djt + dT[1] - 2.f * gjt.y, 0.f)) + EPSF);
            ivt.z = 1.f / (sqrtf(fmaxf(djt + dT[2] - 2.f * gjt.z, 0.f)) + EPSF);
            ivt.w = 1.f / (sqrtf(fmaxf(djt + dT[3] - 2.f * gjt.w, 0.f)) + EPSF);
            *(float4*)&sGJ[r][c4] = gjs;
            *(float4*)&sTJ[r][c4] = gjt;
            *(float4*)&sIJ[r][c4] = ivs;
            *(float4*)&sITJ[r][c4] = ivt;
        }
        // per-thread constants
        const float Gjj = dgS[j], Tjj = dgT[j];
        const float wis1 = 1.f / (sqrtf(fmaxf(dgS[i1] + Gjj - 2.f * g1s, 0.f)) + EPSF);
        const float wit1 = 1.f / (sqrtf(fmaxf(dgT[i1] + Tjj - 2.f * g1t, 0.f)) + EPSF);
        const float wis2 = 1.f / (sqrtf(fmaxf(dgS[i2] + Gjj - 2.f * g2s, 0.f)) + EPSF);
        const float wit2 = 1.f / (sqrtf(fmaxf(dgT[i2] + Tjj - 2.f * g2t, 0.f)) + EPSF);
        const float as1 = (Gjj - g1s) * wis1;
        const float at1 = (Tjj - g1t) * wit1;
        const float as2 = (Gjj - g2s) * wis2;
        const float at2 = (Tjj - g2t) * wit2;
        __syncthreads();   // all arrays ready

        float sum1 = 0.f, sum2 = 0.f;
        for (int c = 0; c < 64; c += 4) {
            const float4 gJ  = *(const float4*)&sGJ[jj][c];
            const float4 iJ  = *(const float4*)&sIJ[jj][c];
            const float4 tJ  = *(const float4*)&sTJ[jj][c];
            const float4 itJ = *(const float4*)&sITJ[jj][c];
            const float4 a1 = *(const float4*)&sGI[ii][c];
            const float4 b1 = *(const float4*)&sTI[ii][c];
            const float4 a2 = *(const float4*)&sGI[ii + 16][c];
            const float4 b2 = *(const float4*)&sTI[ii + 16][c];
            const float gJr[4]  = {gJ.x, gJ.y, gJ.z, gJ.w};
            const float iJr[4]  = {iJ.x, iJ.y, iJ.z, iJ.w};
            const float tJr[4]  = {tJ.x, tJ.y, tJ.z, tJ.w};
            const float itJr[4] = {itJ.x, itJ.y, itJ.z, itJ.w};
            const float a1r[4] = {a1.x, a1.y, a1.z, a1.w};
            const float b1r[4] = {b1.x, b1.y, b1.z, b1.w};
            const float a2r[4] = {a2.x, a2.y, a2.z, a2.w};
            const float b2r[4] = {b2.x, b2.y, b2.z, b2.w};
            #pragma unroll
            for (int e = 0; e < 4; ++e) {
                const float ps1 = fmaf(wis1, a1r[e] - gJr[e], as1) * iJr[e];
                const float pt1 = fmaf(wit1, b1r[e] - tJr[e], at1) * itJr[e];
                const float d1 = ps1 - pt1;
                const float ad1 = fabsf(d1);
                const float m1 = fminf(ad1, 1.f);
                sum1 = fmaf(m1, fmaf(-0.5f, m1, ad1), sum1);

                const float ps2 = fmaf(wis2, a2r[e] - gJr[e], as2) * iJr[e];
                const float pt2 = fmaf(wit2, b2r[e] - tJr[e], at2) * itJr[e];
                const float d2 = ps2 - pt2;
                const float ad2 = fabsf(d2);
                const float m2 = fminf(ad2, 1.f);
                sum2 = fmaf(m2, fmaf(-0.5f, m2, ad2), sum2);
            }
        }
        const float v = block_reduce_sum(sum1 + sum2, red1);
        if (t == 0) ws[OFF_SLOT + SL_ANG + b] = v;
    } else if (b < 768) {
        // ---------------- distance row ----------------
        const int i = b - 512, j = t;
        float gs = 0.f, gt = 0.f, djs = 0.f, djt = 0.f, dis = 0.f, dit = 0.f;
        #pragma unroll
        for (int c = 0; c < 8; ++c) {
            gs  += P[c * 131072u + (unsigned)(i * 256 + j)];
            gt  += P[c * 131072u + 65536u + (unsigned)(i * 256 + j)];
            djs += PD[c * 512 + j];
            djt += PD[c * 512 + 256 + j];
            dis += PD[c * 512 + i];
            dit += PD[c * 512 + 256 + i];
        }
        const float ds = fmaxf(dis + djs - 2.f * gs, 0.f);
        const float dt = fmaxf(dit + djt - 2.f * gt, 0.f);

        // analytic masked pair-sums: sum_{i<j} d = N*tr - sum_all(G)
        const float tr_s = block_reduce_sum(djs, red1);
        const float tr_t = block_reduce_sum(djt, red1);
        const float tv = ws[OFF_TSUM + t];
        const float sum_gs = block_reduce_sum((t < 128) ? tv : 0.f, red1);
        const float sum_gt = block_reduce_sum((t >= 128) ? tv : 0.f, red1);
        const float rs = 1.f / ((256.f * tr_s - sum_gs) / 32640.f + EPSF);
        const float rt = 1.f / ((256.f * tr_t - sum_gt) / 32640.f + EPSF);

        const float dd = ds * rs - dt * rt;
        const float a = fabsf(dd);
        const float m = fminf(a, 1.f);
        const float hv = block_reduce_sum((j > i) ? m * fmaf(-0.5f, m, a) : 0.f, red1);
        if (t == 0) ws[OFF_SLOT + SL_DIST + i] = hv;
    } else {
        // ---------------- contrastive row ----------------
        const int rrow = b - 768, j = t;
        float gs = 0.f;
        if (j >= 128) {
            #pragma unroll
            for (int c = 0; c < 8; ++c)
                gs += P[c * 131072u + (unsigned)(rrow * 256 + j)];
        }
        const float s = (j >= 128) ? 20.f * gs : -INFINITY;
        if (j == 128 + rrow) redS[0] = s;     // diag score
        float mx0 = wave_reduce_max(s);
        __syncthreads();
        if ((t & 63) == 0) red2[t >> 6] = mx0;
        __syncthreads();
        const float mx = fmaxf(fmaxf(red2[0], red2[1]), fmaxf(red2[2], red2[3]));
        const float e = block_reduce_sum((j >= 128) ? expf(s - mx) : 0.f, red1);
        if (t == 0) ws[OFF_SLOT + SL_CON + rrow] = mx + logf(e) - redS[0];
    }
}

// ---------------------------------------------------------------------------
// K3: finalize. 1 block x 256 threads; kernel boundary = coherence point.
// ---------------------------------------------------------------------------
__global__ __launch_bounds__(256) void finalize_kernel(const float* __restrict__ ws,
                                                       float* __restrict__ out) {
    __shared__ float red1[4];
    const int t = threadIdx.x;
    const float* S = ws + OFF_SLOT;
    const float a_ = block_reduce_sum(S[SL_ANG + t] + S[SL_ANG + 256 + t], red1);
    const float d_ = block_reduce_sum(S[SL_DIST + t], red1);
    const float c_ = block_reduce_sum((t < 128) ? S[SL_CON + t] : 0.f, red1);
    if (t == 0) {
        const float contrastive = c_ / 128.f;
        const float dist = d_ / 32640.f;
        const float ang = a_ / 16581120.f;   // 256*255*254
        const float kd = 0.5f * (dist + ang);
        out[0] = contrastive + kd;
        out[1] = contrastive;
        out[2] = kd;
    }
}

extern "C" void kernel_launch(void* const* d_in, const int* in_sizes, int n_in,
                              void* d_out, int out_size, void* d_ws, size_t ws_size,
                              hipStream_t stream) {
    (void)in_sizes; (void)n_in; (void)out_size; (void)ws_size;
    const float* sq = (const float*)d_in[0];
    const float* sp = (const float*)d_in[1];
    const float* tq = (const float*)d_in[2];
    const float* tp = (const float*)d_in[3];
    float* ws  = (float*)d_ws;
    float* out = (float*)d_out;

    gemm_kernel<<<256, 256, 0, stream>>>(sq, sp, tq, tp, ws);
    mega_kernel<<<896, 256, 0, stream>>>(ws);
    finalize_kernel<<<1, 256, 0, stream>>>(ws, out);
}

// Round 9
// 80.521 us; speedup vs baseline: 1.2546x; 1.0381x over previous
//
#include <hip/hip_runtime.h>
#include <math.h>

#define N2   256
#define DIM  768
#define EPSF 1e-8f

// ws layout (float offsets). Every word is written before read on every call
// -> no zero-init needed despite 0xAA poison. Total ~4.2 MB.
// NOTE (measured R6): same-address device atomicAdd costs ~10us/1000 in tail
// serialization -> slots + 1-block finalize kernel is the faster pattern.
// NOTE (measured R4): __threadfence() in hot blocks = per-block L2 writeback/
// invalidate storm (60us angle). Kernel boundaries are the free coherence pt.
// NOTE (R8): prep kernel deleted — consumers sum the 8 split-K partials
// inline and compute diag/INV on the fly; one fewer node.
// NOTE (R9): GEMM moved to bf16 MFMA (fp32->bf16 RNE at staging). All
// downstream uses are symmetric dot-products, so tile-transpose conventions
// cancel; only the k-mapping of the fragments matters (HW-verified layout).
#define OFF_PART  0u          // [8][2][65536] split-K partial Grams (4 MB)
#define OFF_PDIAG 1048576u    // [8][2][256]   partial diagonals
#define OFF_TSUM  1052672u    // [2][8][16]    per-tile partial sums (mat-major)
#define OFF_SLOT  1052928u    // [896] per-block result slots
#define SL_ANG  0     // [512]
#define SL_DIST 512   // [256]
#define SL_CON  768   // [128]

typedef __attribute__((ext_vector_type(8))) short short8;   // 8 bf16 = 4 VGPRs
typedef __attribute__((ext_vector_type(4))) float f32x4;

__device__ inline float wave_reduce_sum(float v) {
    #pragma unroll
    for (int o = 32; o > 0; o >>= 1) v += __shfl_down(v, o, 64);
    return v;
}
__device__ inline float wave_reduce_max(float v) {
    #pragma unroll
    for (int o = 32; o > 0; o >>= 1) v = fmaxf(v, __shfl_down(v, o, 64));
    return v;
}
__device__ inline float block_reduce_sum(float v, volatile float* red) {
    float w = wave_reduce_sum(v);
    __syncthreads();
    if ((threadIdx.x & 63) == 0) red[threadIdx.x >> 6] = w;
    __syncthreads();
    return red[0] + red[1] + red[2] + red[3];
}
__device__ inline const float* rowptr(const float* q, const float* p, int r) {
    return (r < 128) ? (q + r * DIM) : (p + (r - 128) * DIM);
}
__device__ inline unsigned f2bf(float x) {      // fp32 -> bf16 (RNE)
    union { float f; unsigned u; } v; v.f = x;
    return (v.u + 0x7fffu + ((v.u >> 16) & 1u)) >> 16;
}

// ---------------------------------------------------------------------------
// K1: Gram GEMM via bf16 MFMA, split-K-8. 256 blocks x 256 threads.
// b&7 = K-chunk (96), (b>>3)&1 = matrix, b>>4 = 64x64 tile (4x4 grid).
// Wave w owns the 32x32 quadrant (w>>1, w&1): 2x2 MFMA tiles x 3 k-steps.
// Writes partial Gram + partial diagonal + partial tile-sum.
// ---------------------------------------------------------------------------
__global__ __launch_bounds__(256) void gemm_kernel(
        const float* __restrict__ sq, const float* __restrict__ sp,
        const float* __restrict__ tq, const float* __restrict__ tp,
        float* __restrict__ ws) {
    const int b = blockIdx.x, t = threadIdx.x;
    const int c = b & 7, mat = (b >> 3) & 1, tile = b >> 4;
    const int m0 = (tile >> 2) * 64, n0 = (tile & 3) * 64;
    const float* q = mat ? tq : sq;
    const float* p = mat ? tp : sp;

    __shared__ unsigned short Asb[64][104];   // bf16 [row][k], pad->208B rows
    __shared__ unsigned short Bsb[64][104];
    __shared__ float redg[4];

    // staging: 4 threads/row, each converts 6 float4 spanning the 96-k chunk
    const int srow = t >> 2, skq = (t & 3) * 4;
    const int kb = c * 96;
    const float* arow = rowptr(q, p, m0 + srow);
    const float* brow = rowptr(q, p, n0 + srow);
    #pragma unroll
    for (int m = 0; m < 6; ++m) {
        const float4 a4 = *(const float4*)&arow[kb + skq + 16 * m];
        const float4 b4 = *(const float4*)&brow[kb + skq + 16 * m];
        uint2 ap, bp;
        ap.x = f2bf(a4.x) | (f2bf(a4.y) << 16);
        ap.y = f2bf(a4.z) | (f2bf(a4.w) << 16);
        bp.x = f2bf(b4.x) | (f2bf(b4.y) << 16);
        bp.y = f2bf(b4.z) | (f2bf(b4.w) << 16);
        *(uint2*)&Asb[srow][skq + 16 * m] = ap;
        *(uint2*)&Bsb[srow][skq + 16 * m] = bp;
    }
    __syncthreads();

    const int wave = t >> 6, lane = t & 63;
    const int wm = (wave >> 1) * 32, wn = (wave & 1) * 32;
    const int fr = lane & 15;          // fragment row/col
    const int fk = (lane >> 4) * 8;    // fragment k base
    f32x4 acc[2][2] = {{{0.f,0.f,0.f,0.f},{0.f,0.f,0.f,0.f}},
                       {{0.f,0.f,0.f,0.f},{0.f,0.f,0.f,0.f}}};
    #pragma unroll
    for (int kc = 0; kc < 96; kc += 32) {
        const short8 a0 = *(const short8*)&Asb[wm + fr][kc + fk];
        const short8 a1 = *(const short8*)&Asb[wm + 16 + fr][kc + fk];
        const short8 b0 = *(const short8*)&Bsb[wn + fr][kc + fk];
        const short8 b1 = *(const short8*)&Bsb[wn + 16 + fr][kc + fk];
        acc[0][0] = __builtin_amdgcn_mfma_f32_16x16x32_bf16(a0, b0, acc[0][0], 0, 0, 0);
        acc[0][1] = __builtin_amdgcn_mfma_f32_16x16x32_bf16(a0, b1, acc[0][1], 0, 0, 0);
        acc[1][0] = __builtin_amdgcn_mfma_f32_16x16x32_bf16(a1, b0, acc[1][0], 0, 0, 0);
        acc[1][1] = __builtin_amdgcn_mfma_f32_16x16x32_bf16(a1, b1, acc[1][1], 0, 0, 0);
    }

    // epilogue: C/D layout row=(lane>>4)*4+reg, col=lane&15
    float* P = ws + OFF_PART + (unsigned)(c * 2 + mat) * 65536u;
    const int crow0 = (lane >> 4) * 4;
    const int ccol = lane & 15;
    float ts = 0.f;
    #pragma unroll
    for (int ar = 0; ar < 2; ++ar)
        #pragma unroll
        for (int bc = 0; bc < 2; ++bc)
            #pragma unroll
            for (int reg = 0; reg < 4; ++reg) {
                const int row = m0 + wm + ar * 16 + crow0 + reg;
                const int col = n0 + wn + bc * 16 + ccol;
                const float v = acc[ar][bc][reg];
                P[row * 256 + col] = v;
                ts += v;
            }
    if (m0 == n0 && wm == wn && (lane >> 4) == (ccol >> 2)) {
        // diagonal lanes: reg = ccol&3 hits row==col within diagonal tiles
        float* PD = ws + OFF_PDIAG + (unsigned)(c * 2 + mat) * 256u;
        const int reg = lane & 3;
        #pragma unroll
        for (int ar = 0; ar < 2; ++ar)
            PD[m0 + wm + ar * 16 + ccol] = acc[ar][ar][reg];
    }
    const float tsum = block_reduce_sum(ts, redg);
    if (t == 0) ws[OFF_TSUM + (unsigned)(mat * 128 + c * 16 + tile)] = tsum;
}

// ---------------------------------------------------------------------------
// K2: mega kernel. blocks 0..511 angle, 512..767 dist rows, 768..895
// contrastive rows. All consumers sum the 8 split-K partials inline and
// compute diag/INV on the fly.
// ---------------------------------------------------------------------------
__global__ __launch_bounds__(256) void mega_kernel(float* __restrict__ ws) {
    const float* P  = ws + OFF_PART;
    const float* PD = ws + OFF_PDIAG;
    __shared__ float sGJ[16][68], sTJ[16][68], sIJ[16][68], sITJ[16][68];
    __shared__ float sGI[32][68], sTI[32][68];
    __shared__ float dgS[256], dgT[256];
    __shared__ float red1[4], red2[4], redS[1];
    const int b = blockIdx.x, t = threadIdx.x;

    if (b < 512) {
        // ---------------- angle ----------------
        const int k0 = (b & 3) * 64;
        const int j0 = ((b >> 2) & 15) * 16;
        const int i0 = (b >> 6) * 32;
        const int jj = t & 15, ii = t >> 4;
        const int i1 = i0 + ii, i2 = i1 + 16, j = j0 + jj;

        // diag sums (thread t owns index t)
        {
            float as = 0.f, at_ = 0.f;
            #pragma unroll
            for (int c = 0; c < 8; ++c) {
                as  += PD[c * 512 + t];
                at_ += PD[c * 512 + 256 + t];
            }
            dgS[t] = as; dgT[t] = at_;
        }
        // J-side G sums -> registers (1 float4 slot/thread)
        const int r = t >> 4, c4 = (t & 15) * 4;
        float4 gjs = {0,0,0,0}, gjt = {0,0,0,0};
        {
            const unsigned base = (unsigned)((j0 + r) * 256 + k0 + c4);
            #pragma unroll
            for (int c = 0; c < 8; ++c) {
                const float4 a = *(const float4*)&P[c * 131072u + base];
                const float4 e = *(const float4*)&P[c * 131072u + 65536u + base];
                gjs.x += a.x; gjs.y += a.y; gjs.z += a.z; gjs.w += a.w;
                gjt.x += e.x; gjt.y += e.y; gjt.z += e.z; gjt.w += e.w;
            }
        }
        // I-side G sums -> LDS (2 float4 slots/thread)
        #pragma unroll
        for (int s2 = 0; s2 < 2; ++s2) {
            const int slot = t + 256 * s2;
            const int ri = slot >> 4, ci = (slot & 15) * 4;
            const unsigned base = (unsigned)((i0 + ri) * 256 + k0 + ci);
            float4 gs = {0,0,0,0}, gt = {0,0,0,0};
            #pragma unroll
            for (int c = 0; c < 8; ++c) {
                const float4 a = *(const float4*)&P[c * 131072u + base];
                const float4 e = *(const float4*)&P[c * 131072u + 65536u + base];
                gs.x += a.x; gs.y += a.y; gs.z += a.z; gs.w += a.w;
                gt.x += e.x; gt.y += e.y; gt.z += e.z; gt.w += e.w;
            }
            *(float4*)&sGI[ri][ci] = gs;
            *(float4*)&sTI[ri][ci] = gt;
        }
        // per-thread G[i1,j], G[i2,j] partial sums (both mats)
        float g1s = 0.f, g1t = 0.f, g2s = 0.f, g2t = 0.f;
        #pragma unroll
        for (int c = 0; c < 8; ++c) {
            g1s += P[c * 131072u + (unsigned)(i1 * 256 + j)];
            g1t += P[c * 131072u + 65536u + (unsigned)(i1 * 256 + j)];
            g2s += P[c * 131072u + (unsigned)(i2 * 256 + j)];
            g2t += P[c * 131072u + 65536u + (unsigned)(i2 * 256 + j)];
        }
        __syncthreads();   // dgS/dgT ready

        // write J arrays + on-the-fly INV
        {
            const float djs = dgS[j0 + r], djt = dgT[j0 + r];
            float4 ivs, ivt;
            const float* dS = &dgS[k0 + c4];
            const float* dT = &dgT[k0 + c4];
            ivs.x = 1.f / (sqrtf(fmaxf(djs + dS[0] - 2.f * gjs.x, 0.f)) + EPSF);
            ivs.y = 1.f / (sqrtf(fmaxf(djs + dS[1] - 2.f * gjs.y, 0.f)) + EPSF);
            ivs.z = 1.f / (sqrtf(fmaxf(djs + dS[2] - 2.f * gjs.z, 0.f)) + EPSF);
            ivs.w = 1.f / (sqrtf(fmaxf(djs + dS[3] - 2.f * gjs.w, 0.f)) + EPSF);
            ivt.x = 1.f / (sqrtf(fmaxf(djt + dT[0] - 2.f * gjt.x, 0.f)) + EPSF);
            ivt.y = 1.f / (sqrtf(fmaxf(djt + dT[1] - 2.f * gjt.y, 0.f)) + EPSF);
            ivt.z = 1.f / (sqrtf(fmaxf(djt + dT[2] - 2.f * gjt.z, 0.f)) + EPSF);
            ivt.w = 1.f / (sqrtf(fmaxf(djt + dT[3] - 2.f * gjt.w, 0.f)) + EPSF);
            *(float4*)&sGJ[r][c4] = gjs;
            *(float4*)&sTJ[r][c4] = gjt;
            *(float4*)&sIJ[r][c4] = ivs;
            *(float4*)&sITJ[r][c4] = ivt;
        }
        // per-thread constants
        const float Gjj = dgS[j], Tjj = dgT[j];
        const float wis1 = 1.f / (sqrtf(fmaxf(dgS[i1] + Gjj - 2.f * g1s, 0.f)) + EPSF);
        const float wit1 = 1.f / (sqrtf(fmaxf(dgT[i1] + Tjj - 2.f * g1t, 0.f)) + EPSF);
        const float wis2 = 1.f / (sqrtf(fmaxf(dgS[i2] + Gjj - 2.f * g2s, 0.f)) + EPSF);
        const float wit2 = 1.f / (sqrtf(fmaxf(dgT[i2] + Tjj - 2.f * g2t, 0.f)) + EPSF);
        const float as1 = (Gjj - g1s) * wis1;
        const float at1 = (Tjj - g1t) * wit1;
        const float as2 = (Gjj - g2s) * wis2;
        const float at2 = (Tjj - g2t) * wit2;
        __syncthreads();   // all arrays ready

        float sum1 = 0.f, sum2 = 0.f;
        for (int c = 0; c < 64; c += 4) {
            const float4 gJ  = *(const float4*)&sGJ[jj][c];
            const float4 iJ  = *(const float4*)&sIJ[jj][c];
            const float4 tJ  = *(const float4*)&sTJ[jj][c];
            const float4 itJ = *(const float4*)&sITJ[jj][c];
            const float4 a1 = *(const float4*)&sGI[ii][c];
            const float4 b1 = *(const float4*)&sTI[ii][c];
            const float4 a2 = *(const float4*)&sGI[ii + 16][c];
            const float4 b2 = *(const float4*)&sTI[ii + 16][c];
            const float gJr[4]  = {gJ.x, gJ.y, gJ.z, gJ.w};
            const float iJr[4]  = {iJ.x, iJ.y, iJ.z, iJ.w};
            const float tJr[4]  = {tJ.x, tJ.y, tJ.z, tJ.w};
            const float itJr[4] = {itJ.x, itJ.y, itJ.z, itJ.w};
            const float a1r[4] = {a1.x, a1.y, a1.z, a1.w};
            const float b1r[4] = {b1.x, b1.y, b1.z, b1.w};
            const float a2r[4] = {a2.x, a2.y, a2.z, a2.w};
            const float b2r[4] = {b2.x, b2.y, b2.z, b2.w};
            #pragma unroll
            for (int e = 0; e < 4; ++e) {
                const float ps1 = fmaf(wis1, a1r[e] - gJr[e], as1) * iJr[e];
                const float pt1 = fmaf(wit1, b1r[e] - tJr[e], at1) * itJr[e];
                const float d1 = ps1 - pt1;
                const float ad1 = fabsf(d1);
                const float m1 = fminf(ad1, 1.f);
                sum1 = fmaf(m1, fmaf(-0.5f, m1, ad1), sum1);

                const float ps2 = fmaf(wis2, a2r[e] - gJr[e], as2) * iJr[e];
                const float pt2 = fmaf(wit2, b2r[e] - tJr[e], at2) * itJr[e];
                const float d2 = ps2 - pt2;
                const float ad2 = fabsf(d2);
                const float m2 = fminf(ad2, 1.f);
                sum2 = fmaf(m2, fmaf(-0.5f, m2, ad2), sum2);
            }
        }
        const float v = block_reduce_sum(sum1 + sum2, red1);
        if (t == 0) ws[OFF_SLOT + SL_ANG + b] = v;
    } else if (b < 768) {
        // ---------------- distance row ----------------
        const int i = b - 512, j = t;
        float gs = 0.f, gt = 0.f, djs = 0.f, djt = 0.f, dis = 0.f, dit = 0.f;
        #pragma unroll
        for (int c = 0; c < 8; ++c) {
            gs  += P[c * 131072u + (unsigned)(i * 256 + j)];
            gt  += P[c * 131072u + 65536u + (unsigned)(i * 256 + j)];
            djs += PD[c * 512 + j];
            djt += PD[c * 512 + 256 + j];
            dis += PD[c * 512 + i];
            dit += PD[c * 512 + 256 + i];
        }
        const float ds = fmaxf(dis + djs - 2.f * gs, 0.f);
        const float dt = fmaxf(dit + djt - 2.f * gt, 0.f);

        // analytic masked pair-sums: sum_{i<j} d = N*tr - sum_all(G)
        const float tr_s = block_reduce_sum(djs, red1);
        const float tr_t = block_reduce_sum(djt, red1);
        const float tv = ws[OFF_TSUM + t];
        const float sum_gs = block_reduce_sum((t < 128) ? tv : 0.f, red1);
        const float sum_gt = block_reduce_sum((t >= 128) ? tv : 0.f, red1);
        const float rs = 1.f / ((256.f * tr_s - sum_gs) / 32640.f + EPSF);
        const float rt = 1.f / ((256.f * tr_t - sum_gt) / 32640.f + EPSF);

        const float dd = ds * rs - dt * rt;
        const float a = fabsf(dd);
        const float m = fminf(a, 1.f);
        const float hv = block_reduce_sum((j > i) ? m * fmaf(-0.5f, m, a) : 0.f, red1);
        if (t == 0) ws[OFF_SLOT + SL_DIST + i] = hv;
    } else {
        // ---------------- contrastive row ----------------
        const int rrow = b - 768, j = t;
        float gs = 0.f;
        if (j >= 128) {
            #pragma unroll
            for (int c = 0; c < 8; ++c)
                gs += P[c * 131072u + (unsigned)(rrow * 256 + j)];
        }
        const float s = (j >= 128) ? 20.f * gs : -INFINITY;
        if (j == 128 + rrow) redS[0] = s;     // diag score
        float mx0 = wave_reduce_max(s);
        __syncthreads();
        if ((t & 63) == 0) red2[t >> 6] = mx0;
        __syncthreads();
        const float mx = fmaxf(fmaxf(red2[0], red2[1]), fmaxf(red2[2], red2[3]));
        const float e = block_reduce_sum((j >= 128) ? expf(s - mx) : 0.f, red1);
        if (t == 0) ws[OFF_SLOT + SL_CON + rrow] = mx + logf(e) - redS[0];
    }
}

// ---------------------------------------------------------------------------
// K3: finalize. 1 block x 256 threads; kernel boundary = coherence point.
// ---------------------------------------------------------------------------
__global__ __launch_bounds__(256) void finalize_kernel(const float* __restrict__ ws,
                                                       float* __restrict__ out) {
    __shared__ float red1[4];
    const int t = threadIdx.x;
    const float* S = ws + OFF_SLOT;
    const float a_ = block_reduce_sum(S[SL_ANG + t] + S[SL_ANG + 256 + t], red1);
    const float d_ = block_reduce_sum(S[SL_DIST + t], red1);
    const float c_ = block_reduce_sum((t < 128) ? S[SL_CON + t] : 0.f, red1);
    if (t == 0) {
        const float contrastive = c_ / 128.f;
        const float dist = d_ / 32640.f;
        const float ang = a_ / 16581120.f;   // 256*255*254
        const float kd = 0.5f * (dist + ang);
        out[0] = contrastive + kd;
        out[1] = contrastive;
        out[2] = kd;
    }
}

extern "C" void kernel_launch(void* const* d_in, const int* in_sizes, int n_in,
                              void* d_out, int out_size, void* d_ws, size_t ws_size,
                              hipStream_t stream) {
    (void)in_sizes; (void)n_in; (void)out_size; (void)ws_size;
    const float* sq = (const float*)d_in[0];
    const float* sp = (const float*)d_in[1];
    const float* tq = (const float*)d_in[2];
    const float* tp = (const float*)d_in[3];
    float* ws  = (float*)d_ws;
    float* out = (float*)d_out;

    gemm_kernel<<<256, 256, 0, stream>>>(sq, sp, tq, tp, ws);
    mega_kernel<<<896, 256, 0, stream>>>(ws);
    finalize_kernel<<<1, 256, 0, stream>>>(ws, out);
}